// Round 17
// baseline (1381.289 us; speedup 1.0000x reference)
//
#include <hip/hip_runtime.h>
#include <math.h>

#define D_MODEL 1024
#define NHEADS 16
#define DHEAD 64
#define FDIM 4096
#define NLAYERS 6
#define BATCH 2
#define SEQ 1024
#define NROWS (BATCH*SEQ)
#define VOCAB 32000

typedef __attribute__((ext_vector_type(4))) float f32x4;
typedef __attribute__((ext_vector_type(4))) __bf16 bf16x4;
typedef __attribute__((ext_vector_type(8))) __bf16 bf16x8;

__device__ __forceinline__ void gll16(const void* g, void* l) {
  __builtin_amdgcn_global_load_lds(
      (const __attribute__((address_space(1))) unsigned int*)g,
      (__attribute__((address_space(3))) unsigned int*)l, 16, 0, 0);
}

// W [K][N] f32 (per-layer stride K*N) -> Wt [N][K] bf16
__global__ __launch_bounds__(256) void transpose_w(
    const float* __restrict__ W, __bf16* __restrict__ Wt, int K, int N) {
  __shared__ __bf16 Ls[64][68];
  const size_t moff = (size_t)blockIdx.z * K * N;
  const float* Wl = W + moff;
  __bf16* Wtl = Wt + moff;
  const int n0 = blockIdx.x * 64, k0 = blockIdx.y * 64;
  const int tid = threadIdx.x;
  #pragma unroll
  for (int p = 0; p < 4; ++p) {
    int e = tid + p * 256;
    int r = e >> 4, c4 = (e & 15) * 4;
    float4 v = *(const float4*)&Wl[(size_t)(k0 + r) * N + n0 + c4];
    Ls[c4 + 0][r] = (__bf16)v.x; Ls[c4 + 1][r] = (__bf16)v.y;
    Ls[c4 + 2][r] = (__bf16)v.z; Ls[c4 + 3][r] = (__bf16)v.w;
  }
  __syncthreads();
  #pragma unroll
  for (int p = 0; p < 4; ++p) {
    int e = tid + p * 256;
    int r2 = e >> 4, c8 = (e & 15) * 4;
    bf16x4 o{Ls[r2][c8], Ls[r2][c8 + 1], Ls[r2][c8 + 2], Ls[r2][c8 + 3]};
    *(bf16x4*)&Wtl[(size_t)(n0 + r2) * K + k0 + c8] = o;
  }
}

struct GemmP {
  const __bf16* A;
  const __bf16* W[3];   // [N][K] bf16
  const float* B[3];
  void* C[3];
  int N, K;
};

// C[M,N] = act(A[M,K] @ Wt[N,K]^T + bias). BN=128, BK=64.
// 2-phase dbuf staging (global_load_lds), pre-swizzled-source LDS swizzle,
// bijective XCD remap. BM in {32, 64, 128}.
template<int BM, int RELU, int OUTF32>
__global__ __launch_bounds__(256) void gemm_bf16(GemmP g) {
  constexpr int BK = 64;
  const __bf16* __restrict__ A = g.A;
  const __bf16* __restrict__ W = g.W[blockIdx.z];
  const float* __restrict__ bias = g.B[blockIdx.z];
  const int N = g.N, K = g.K;

  __shared__ __bf16 As[2][BM * BK];
  __shared__ __bf16 Bs[2][128 * BK];

  const int tid = threadIdx.x;
  const int lane = tid & 63, w = tid >> 6;

  const int gx = gridDim.x;
  const int nblk = gx * gridDim.y;
  const int id = blockIdx.x + blockIdx.y * gx;
  const int per = nblk >> 3;
  const int sid = (id & 7) * per + (id >> 3);
  const int row0 = (sid % gx) * BM;
  const int col0 = (sid / gx) * 128;

  const int wm = w >> 1, wn = w & 1;
  const int lr = lane & 15, rsw = lr & 7;

  constexpr int MI = BM / 32;
  f32x4 acc[MI][4] = {};

  const int swg = ((lane & 7) ^ (lane >> 3)) * 8;
  const __bf16* Ag = A + (size_t)(row0 + w * (BM / 4) + (lane >> 3)) * K + swg;
  const __bf16* Wg = W + (size_t)(col0 + w * 32 + (lane >> 3)) * K + swg;

  const int NT = K / BK;

  auto stage = [&](int buf, int t) {
    const int k0 = t * BK;
    #pragma unroll
    for (int s = 0; s < BM / 32; ++s)
      gll16(Ag + (size_t)s * 8 * K + k0, &As[buf][(w * (BM / 4) + s * 8) * BK]);
    #pragma unroll
    for (int s = 0; s < 4; ++s)
      gll16(Wg + (size_t)s * 8 * K + k0, &Bs[buf][(w * 32 + s * 8) * BK]);
  };

  stage(0, 0);
  __syncthreads();

  int cur = 0;
  for (int t = 0; t < NT; ++t) {
    if (t + 1 < NT) stage(cur ^ 1, t + 1);
    #pragma unroll
    for (int kk = 0; kk < 2; ++kk) {
      const int gsw = ((kk * 4 + (lane >> 4)) ^ rsw) * 8;
      bf16x8 af[MI], bf[4];
      #pragma unroll
      for (int i = 0; i < MI; ++i)
        af[i] = *(const bf16x8*)&As[cur][(wm * (BM / 2) + i * 16 + lr) * BK + gsw];
      #pragma unroll
      for (int j = 0; j < 4; ++j)
        bf[j] = *(const bf16x8*)&Bs[cur][(wn * 64 + j * 16 + lr) * BK + gsw];
      #pragma unroll
      for (int i = 0; i < MI; ++i)
        #pragma unroll
        for (int j = 0; j < 4; ++j)
          acc[i][j] = __builtin_amdgcn_mfma_f32_16x16x32_bf16(af[i], bf[j], acc[i][j], 0, 0, 0);
    }
    __syncthreads();
    cur ^= 1;
  }

  #pragma unroll
  for (int i = 0; i < MI; ++i) {
    #pragma unroll
    for (int j = 0; j < 4; ++j) {
      int col = col0 + wn * 64 + j * 16 + lr;
      float bb = bias[col];
      #pragma unroll
      for (int r = 0; r < 4; ++r) {
        int row = row0 + wm * (BM / 2) + i * 16 + (lane >> 4) * 4 + r;
        float v = acc[i][j][r] + bb;
        if (RELU) v = fmaxf(v, 0.0f);
        if (OUTF32) ((float*)g.C[blockIdx.z])[(size_t)row * N + col] = v;
        else ((__bf16*)g.C[blockIdx.z])[(size_t)row * N + col] = (__bf16)v;
      }
    }
  }
}

// 256x256-tile GEMM (2-phase, best measured for vocab). 512 thr = 8 waves,
// wave tile 128x64, BK=64, dbuf 128KB dynamic LDS.
__global__ __launch_bounds__(512, 1) void gemm_256(
    const __bf16* __restrict__ A, const __bf16* __restrict__ W,
    const float* __restrict__ bias, float* __restrict__ C, int N, int K) {
  extern __shared__ __bf16 sm[];
  __bf16* As = sm;                 // [2][256*64]
  __bf16* Bs = sm + 2 * 256 * 64;  // [2][256*64]

  const int tid = threadIdx.x;
  const int lane = tid & 63, w = tid >> 6;

  const int gx = gridDim.x;
  const int nblk = gx * gridDim.y;
  const int id = blockIdx.x + blockIdx.y * gx;
  const int per = nblk >> 3;
  const int sid = (id & 7) * per + (id >> 3);
  const int row0 = (sid % gx) * 256;
  const int col0 = (sid / gx) * 256;

  const int wr = w >> 2, wc = w & 3;
  const int lr = lane & 15;

  f32x4 acc[8][4] = {};

  const int swg = ((lane & 7) ^ (lane >> 3)) * 8;
  const __bf16* Ag = A + (size_t)(row0 + w * 32 + (lane >> 3)) * K + swg;
  const __bf16* Wg = W + (size_t)(col0 + w * 32 + (lane >> 3)) * K + swg;

  const int NT = K / 64;

  auto stage = [&](int buf, int t) {
    const int k0 = t * 64;
    #pragma unroll
    for (int s = 0; s < 4; ++s) {
      gll16(Ag + (size_t)(s * 8) * K + k0, &As[buf * 16384 + (w * 32 + s * 8) * 64]);
      gll16(Wg + (size_t)(s * 8) * K + k0, &Bs[buf * 16384 + (w * 32 + s * 8) * 64]);
    }
  };

  stage(0, 0);
  __syncthreads();

  int cur = 0;
  for (int t = 0; t < NT; ++t) {
    if (t + 1 < NT) stage(cur ^ 1, t + 1);
    #pragma unroll
    for (int kk = 0; kk < 2; ++kk) {
      bf16x8 af[8], bf[4];
      #pragma unroll
      for (int i = 0; i < 8; ++i) {
        int row = wr * 128 + i * 16 + lr;
        af[i] = *(const bf16x8*)&As[cur * 16384 + row * 64 +
                                    (((kk * 4 + (lane >> 4)) ^ (row & 7)) * 8)];
      }
      #pragma unroll
      for (int j = 0; j < 4; ++j) {
        int row = wc * 64 + j * 16 + lr;
        bf[j] = *(const bf16x8*)&Bs[cur * 16384 + row * 64 +
                                    (((kk * 4 + (lane >> 4)) ^ (row & 7)) * 8)];
      }
      #pragma unroll
      for (int i = 0; i < 8; ++i)
        #pragma unroll
        for (int j = 0; j < 4; ++j)
          acc[i][j] = __builtin_amdgcn_mfma_f32_16x16x32_bf16(af[i], bf[j], acc[i][j], 0, 0, 0);
    }
    __syncthreads();
    cur ^= 1;
  }

  #pragma unroll
  for (int i = 0; i < 8; ++i) {
    #pragma unroll
    for (int j = 0; j < 4; ++j) {
      int col = col0 + wc * 64 + j * 16 + lr;
      float bb = bias[col];
      #pragma unroll
      for (int r = 0; r < 4; ++r) {
        int row = row0 + wr * 128 + i * 16 + (lane >> 4) * 4 + r;
        C[(size_t)row * N + col] = acc[i][j][r] + bb;
      }
    }
  }
}

// MFMA flash attention, bf16 in/out. Causal-balanced (block bx does q-tiles
// bx and 15-bx) + double-buffered K/V staging: one barrier per chunk,
// stage of chunk ck+1 issued before compute of ck (latency hides).
__global__ __launch_bounds__(256) void attn_kernel(
    const __bf16* __restrict__ Q, const __bf16* __restrict__ K,
    const __bf16* __restrict__ V, __bf16* __restrict__ O) {
  __shared__ __bf16 Ks[2][64 * 64];   // [buf][kv][d], swizzled
  __shared__ __bf16 Vts[2][64 * 64];  // [buf][d][kv], swizzled
  __shared__ __bf16 Psm[4][16 * 64];  // per-wave P [q][kv], swizzled

  const int tid = threadIdx.x;
  const int lane = tid & 63, w = tid >> 6;
  const int bh = blockIdx.y;
  const int b = bh >> 4, h = bh & 15;
  const size_t base = ((size_t)b * SEQ) * D_MODEL + (size_t)h * DHEAD;

  const int lr = lane & 15;
  const int lk = (lane >> 4) * 8;
  const int NQT = SEQ / 64;  // 16

  // stage chunk (kv0) into LDS buf: reg-staged, swizzled
  auto stage = [&](int buf, int kv0) {
    #pragma unroll
    for (int c = 0; c < 2; ++c) {
      int e = tid + c * 256;
      int r = e >> 3, d8 = (e & 7) * 8;
      const size_t grow = base + (size_t)(kv0 + r) * D_MODEL + d8;
      bf16x8 kv = *(const bf16x8*)&K[grow];
      *(bf16x8*)&Ks[buf][(r * 64 + d8) ^ ((r & 7) << 3)] = kv;
      bf16x8 vv = *(const bf16x8*)&V[grow];
      #pragma unroll
      for (int j = 0; j < 8; ++j)
        Vts[buf][((d8 + j) * 64 + r) ^ (((d8 + j) & 7) << 3)] = vv[j];
    }
  };

  #pragma unroll
  for (int p = 0; p < 2; ++p) {
    const int qt = p == 0 ? (int)blockIdx.x : (NQT - 1 - (int)blockIdx.x);
    const int q0 = qt * 64;

    bf16x8 qa[2];
    {
      const __bf16* qp = Q + base + (size_t)(q0 + w * 16 + lr) * D_MODEL;
      qa[0] = *(const bf16x8*)&qp[lk];
      qa[1] = *(const bf16x8*)&qp[32 + lk];
    }

    f32x4 o_acc[4] = {};
    float m[4], l[4];
    #pragma unroll
    for (int r = 0; r < 4; ++r) { m[r] = -1e30f; l[r] = 0.0f; }

    const int nck = qt + 1;

    __syncthreads();  // prior tile's buf-0 reads done before restage
    stage(0, 0);

    for (int ck = 0; ck < nck; ++ck) {
      const int cur = ck & 1;
      __syncthreads();  // buf[cur] writes (staged last iter) visible
      if (ck + 1 < nck) stage(cur ^ 1, (ck + 1) * 64);

      const int kv0 = ck * 64;
      f32x4 s_acc[4] = {};
      #pragma unroll
      for (int t = 0; t < 4; ++t) {
        int row = t * 16 + lr;
        #pragma unroll
        for (int hh = 0; hh < 2; ++hh) {
          bf16x8 kb = *(const bf16x8*)&Ks[cur][(row * 64 + hh * 32 + lk) ^ ((row & 7) << 3)];
          s_acc[t] = __builtin_amdgcn_mfma_f32_16x16x32_bf16(qa[hh], kb, s_acc[t], 0, 0, 0);
        }
      }

      const bool diag = (ck == nck - 1);
      #pragma unroll
      for (int t = 0; t < 4; ++t) {
        int kvg = kv0 + t * 16 + lr;
        #pragma unroll
        for (int r = 0; r < 4; ++r) {
          float sv = s_acc[t][r] * 0.125f;
          if (diag) {
            int qg = q0 + w * 16 + (lane >> 4) * 4 + r;
            if (kvg > qg) sv = -1e30f;
          }
          s_acc[t][r] = sv;
        }
      }

      #pragma unroll
      for (int r = 0; r < 4; ++r) {
        float cm = fmaxf(fmaxf(s_acc[0][r], s_acc[1][r]), fmaxf(s_acc[2][r], s_acc[3][r]));
        #pragma unroll
        for (int off = 1; off < 16; off <<= 1) cm = fmaxf(cm, __shfl_xor(cm, off, 64));
        float newm = fmaxf(m[r], cm);
        float sc = __expf(m[r] - newm);
        m[r] = newm;
        float psum = 0.0f;
        #pragma unroll
        for (int t = 0; t < 4; ++t) {
          float pv = __expf(s_acc[t][r] - newm);
          s_acc[t][r] = pv;
          psum += pv;
        }
        #pragma unroll
        for (int off = 1; off < 16; off <<= 1) psum += __shfl_xor(psum, off, 64);
        l[r] = l[r] * sc + psum;
        #pragma unroll
        for (int t = 0; t < 4; ++t) o_acc[t][r] *= sc;
      }

      #pragma unroll
      for (int t = 0; t < 4; ++t) {
        #pragma unroll
        for (int r = 0; r < 4; ++r) {
          int ql = (lane >> 4) * 4 + r;
          Psm[w][(ql * 64 + t * 16 + lr) ^ ((ql & 7) << 3)] = (__bf16)(s_acc[t][r]);
        }
      }

      bf16x8 pa[2];
      #pragma unroll
      for (int hh = 0; hh < 2; ++hh)
        pa[hh] = *(const bf16x8*)&Psm[w][(lr * 64 + hh * 32 + lk) ^ ((lr & 7) << 3)];
      #pragma unroll
      for (int t = 0; t < 4; ++t) {
        int row = t * 16 + lr;
        #pragma unroll
        for (int hh = 0; hh < 2; ++hh) {
          bf16x8 vb = *(const bf16x8*)&Vts[cur][(row * 64 + hh * 32 + lk) ^ ((row & 7) << 3)];
          o_acc[t] = __builtin_amdgcn_mfma_f32_16x16x32_bf16(pa[hh], vb, o_acc[t], 0, 0, 0);
        }
      }
    }

    #pragma unroll
    for (int r = 0; r < 4; ++r) {
      float inv = 1.0f / l[r];
      int qg = q0 + w * 16 + (lane >> 4) * 4 + r;
      #pragma unroll
      for (int t = 0; t < 4; ++t)
        O[base + (size_t)qg * D_MODEL + t * 16 + lr] = (__bf16)(o_acc[t][r] * inv);
    }
  }
}

// Out = LN(X (+ R)) * g + b. Wave-per-row: 4 rows/block, 64 lanes/row,
// 16 elems/lane, pure shfl reduction (no LDS, no barrier).
template<int HASRES>
__global__ __launch_bounds__(256) void addln_kernel(
    const __bf16* __restrict__ X, const __bf16* __restrict__ Rr,
    const float* __restrict__ g, const float* __restrict__ bb,
    __bf16* __restrict__ Out) {
  const int row = blockIdx.x * 4 + (threadIdx.x >> 6);
  const int lane = threadIdx.x & 63;
  const int d0 = lane * 16;
  const size_t rb = (size_t)row * D_MODEL + d0;

  bf16x8 x0 = *(const bf16x8*)&X[rb];
  bf16x8 x1 = *(const bf16x8*)&X[rb + 8];
  float v[16];
  float s = 0.0f, ss = 0.0f;
  if (HASRES) {
    bf16x8 r0 = *(const bf16x8*)&Rr[rb];
    bf16x8 r1 = *(const bf16x8*)&Rr[rb + 8];
    #pragma unroll
    for (int i = 0; i < 8; ++i) {
      v[i] = (float)x0[i] + (float)r0[i];
      v[8 + i] = (float)x1[i] + (float)r1[i];
    }
  } else {
    #pragma unroll
    for (int i = 0; i < 8; ++i) { v[i] = (float)x0[i]; v[8 + i] = (float)x1[i]; }
  }
  #pragma unroll
  for (int i = 0; i < 16; ++i) { s += v[i]; ss += v[i] * v[i]; }
  #pragma unroll
  for (int off = 32; off; off >>= 1) { s += __shfl_xor(s, off, 64); ss += __shfl_xor(ss, off, 64); }
  float mean = s * (1.0f / D_MODEL);
  float var = ss * (1.0f / D_MODEL) - mean * mean;
  float rs = rsqrtf(var + 1e-5f);

  bf16x8 o0, o1;
  #pragma unroll
  for (int c = 0; c < 4; ++c) {
    float4 gv = *(const float4*)&g[d0 + c * 4];
    float4 bv = *(const float4*)&bb[d0 + c * 4];
    float go[4] = {gv.x, gv.y, gv.z, gv.w};
    float bo[4] = {bv.x, bv.y, bv.z, bv.w};
    #pragma unroll
    for (int i = 0; i < 4; ++i) {
      int e = c * 4 + i;
      __bf16 r = (__bf16)((v[e] - mean) * rs * go[i] + bo[i]);
      if (e < 8) o0[e] = r; else o1[e - 8] = r;
    }
  }
  *(bf16x8*)&Out[rb] = o0;
  *(bf16x8*)&Out[rb + 8] = o1;
}

// H[row,d] = embed[x[row],d]*sqrt(D) + PE(row%S, d), bf16 out.
__global__ __launch_bounds__(256) void embed_kernel(
    const int* __restrict__ x, const float* __restrict__ embed,
    __bf16* __restrict__ H) {
  const int row = blockIdx.x;
  const int spos = row & (SEQ - 1);
  const int tok = x[row];
  const int tid = threadIdx.x;
  const int d0 = tid * 4;
  float4 e4 = *(const float4*)&embed[(size_t)tok * D_MODEL + d0];
  float ev[4] = {e4.x, e4.y, e4.z, e4.w};
  bf16x4 ov;
  #pragma unroll
  for (int p = 0; p < 2; ++p) {
    int d = d0 + 2 * p;
    float div = expf((float)d * (-9.2103403719761836f / (float)D_MODEL));
    float ang = (float)spos * div;
    float sv, cv;
    __sincosf(ang, &sv, &cv);
    ov[2 * p] = (__bf16)(ev[2 * p] * 32.0f + sv);
    ov[2 * p + 1] = (__bf16)(ev[2 * p + 1] * 32.0f + cv);
  }
  *(bf16x4*)&H[(size_t)row * D_MODEL + d0] = ov;
}

extern "C" void kernel_launch(void* const* d_in, const int* in_sizes, int n_in,
                              void* d_out, int out_size, void* d_ws, size_t ws_size,
                              hipStream_t stream) {
  const int* x = (const int*)d_in[0];
  const float* embed = (const float*)d_in[2];
  const float* wq = (const float*)d_in[3];
  const float* bq = (const float*)d_in[4];
  const float* wk = (const float*)d_in[5];
  const float* bk = (const float*)d_in[6];
  const float* wv = (const float*)d_in[7];
  const float* bv = (const float*)d_in[8];
  const float* wo = (const float*)d_in[9];
  const float* bo = (const float*)d_in[10];
  const float* w1 = (const float*)d_in[11];
  const float* b1 = (const float*)d_in[12];
  const float* w2 = (const float*)d_in[13];
  const float* b2 = (const float*)d_in[14];
  const float* ln1g = (const float*)d_in[15];
  const float* ln1b = (const float*)d_in[16];
  const float* ln2g = (const float*)d_in[17];
  const float* ln2b = (const float*)d_in[18];
  const float* lnfg = (const float*)d_in[19];
  const float* lnfb = (const float*)d_in[20];
  const float* pw = (const float*)d_in[21];
  const float* pb = (const float*)d_in[22];
  float* out = (float*)d_out;

  // ---- workspace layout (bf16) ----
  char* wsp = (char*)d_ws;
  size_t off = 0;
  auto alloc = [&](size_t bytes) {
    void* p = wsp + off; off = (off + bytes + 255) & ~(size_t)255; return p;
  };
  const size_t RD2 = (size_t)NROWS * D_MODEL * 2;
  __bf16* Xb   = (__bf16*)alloc(RD2);
  __bf16* Qb   = (__bf16*)alloc(RD2);
  __bf16* Kb   = (__bf16*)alloc(RD2);
  __bf16* Vb   = (__bf16*)alloc(RD2);
  __bf16* CTXb = (__bf16*)alloc(RD2);
  __bf16* Tb   = (__bf16*)alloc(RD2);
  __bf16* H1b  = (__bf16*)alloc(RD2);
  __bf16* FFb  = Qb;  // alias: FF (16MB) over Qb..CTXb, dead when FFN1 runs
  const size_t DD = (size_t)D_MODEL * D_MODEL;
  const size_t DF = (size_t)D_MODEL * FDIM;
  __bf16* wqt = (__bf16*)alloc(NLAYERS * DD * 2);
  __bf16* wkt = (__bf16*)alloc(NLAYERS * DD * 2);
  __bf16* wvt = (__bf16*)alloc(NLAYERS * DD * 2);
  __bf16* wot = (__bf16*)alloc(NLAYERS * DD * 2);
  __bf16* w1t = (__bf16*)alloc(NLAYERS * DF * 2);
  __bf16* w2t = (__bf16*)alloc(NLAYERS * DF * 2);
  __bf16* pwt = (__bf16*)alloc((size_t)D_MODEL * VOCAB * 2);

  // ---- weight transpose+convert (runs each replay) ----
  transpose_w<<<dim3(16, 16, NLAYERS), 256, 0, stream>>>(wq, wqt, D_MODEL, D_MODEL);
  transpose_w<<<dim3(16, 16, NLAYERS), 256, 0, stream>>>(wk, wkt, D_MODEL, D_MODEL);
  transpose_w<<<dim3(16, 16, NLAYERS), 256, 0, stream>>>(wv, wvt, D_MODEL, D_MODEL);
  transpose_w<<<dim3(16, 16, NLAYERS), 256, 0, stream>>>(wo, wot, D_MODEL, D_MODEL);
  transpose_w<<<dim3(64, 16, NLAYERS), 256, 0, stream>>>(w1, w1t, D_MODEL, FDIM);
  transpose_w<<<dim3(16, 64, NLAYERS), 256, 0, stream>>>(w2, w2t, FDIM, D_MODEL);
  transpose_w<<<dim3(500, 16, 1), 256, 0, stream>>>(pw, pwt, D_MODEL, VOCAB);

  embed_kernel<<<NROWS, 256, 0, stream>>>(x, embed, Xb);

  for (int l = 0; l < NLAYERS; ++l) {
    GemmP g{};
    g.A = Xb; g.N = D_MODEL; g.K = D_MODEL;
    g.W[0] = wqt + l * DD; g.W[1] = wkt + l * DD; g.W[2] = wvt + l * DD;
    g.B[0] = bq + l * D_MODEL; g.B[1] = bk + l * D_MODEL; g.B[2] = bv + l * D_MODEL;
    g.C[0] = Qb; g.C[1] = Kb; g.C[2] = Vb;
    gemm_bf16<64, 0, 0><<<dim3(NROWS / 64, D_MODEL / 128, 3), 256, 0, stream>>>(g);

    attn_kernel<<<dim3(SEQ / 128, BATCH * NHEADS), 256, 0, stream>>>(Qb, Kb, Vb, CTXb);

    GemmP go{};
    go.A = CTXb; go.N = D_MODEL; go.K = D_MODEL;
    go.W[0] = wot + l * DD; go.B[0] = bo + l * D_MODEL; go.C[0] = Tb;
    gemm_bf16<32, 0, 0><<<dim3(NROWS / 32, D_MODEL / 128, 1), 256, 0, stream>>>(go);

    addln_kernel<1><<<NROWS / 4, 256, 0, stream>>>(Xb, Tb, ln1g + l * D_MODEL, ln1b + l * D_MODEL, H1b);

    GemmP g1{};
    g1.A = H1b; g1.N = FDIM; g1.K = D_MODEL;
    g1.W[0] = w1t + l * DF; g1.B[0] = b1 + l * FDIM; g1.C[0] = FFb;
    gemm_bf16<128, 1, 0><<<dim3(NROWS / 128, FDIM / 128, 1), 256, 0, stream>>>(g1);

    GemmP g2{};
    g2.A = FFb; g2.N = D_MODEL; g2.K = FDIM;
    g2.W[0] = w2t + l * DF; g2.B[0] = b2 + l * D_MODEL; g2.C[0] = Tb;
    gemm_bf16<32, 0, 0><<<dim3(NROWS / 32, D_MODEL / 128, 1), 256, 0, stream>>>(g2);

    addln_kernel<1><<<NROWS / 4, 256, 0, stream>>>(H1b, Tb, ln2g + l * D_MODEL, ln2b + l * D_MODEL, Xb);
  }

  addln_kernel<0><<<NROWS / 4, 256, 0, stream>>>(Xb, nullptr, lnfg, lnfb, H1b);

  // vocab projection: 256x256-tile 2-phase kernel, 128KB dynamic LDS
  hipFuncSetAttribute((const void*)gemm_256,
                      hipFuncAttributeMaxDynamicSharedMemorySize, 131072);
  gemm_256<<<dim3(NROWS / 256, VOCAB / 256), 512, 131072, stream>>>(
      H1b, pwt, pb, out, VOCAB, D_MODEL);
}

// Round 18
// 1372.141 us; speedup vs baseline: 1.0067x; 1.0067x over previous
//
#include <hip/hip_runtime.h>
#include <math.h>

#define D_MODEL 1024
#define NHEADS 16
#define DHEAD 64
#define FDIM 4096
#define NLAYERS 6
#define BATCH 2
#define SEQ 1024
#define NROWS (BATCH*SEQ)
#define VOCAB 32000

typedef __attribute__((ext_vector_type(4))) float f32x4;
typedef __attribute__((ext_vector_type(4))) __bf16 bf16x4;
typedef __attribute__((ext_vector_type(8))) __bf16 bf16x8;

__device__ __forceinline__ void gll16(const void* g, void* l) {
  __builtin_amdgcn_global_load_lds(
      (const __attribute__((address_space(1))) unsigned int*)g,
      (__attribute__((address_space(3))) unsigned int*)l, 16, 0, 0);
}

// W [K][N] f32 (per-layer stride K*N) -> Wt [N][K] bf16
__global__ __launch_bounds__(256) void transpose_w(
    const float* __restrict__ W, __bf16* __restrict__ Wt, int K, int N) {
  __shared__ __bf16 Ls[64][68];
  const size_t moff = (size_t)blockIdx.z * K * N;
  const float* Wl = W + moff;
  __bf16* Wtl = Wt + moff;
  const int n0 = blockIdx.x * 64, k0 = blockIdx.y * 64;
  const int tid = threadIdx.x;
  #pragma unroll
  for (int p = 0; p < 4; ++p) {
    int e = tid + p * 256;
    int r = e >> 4, c4 = (e & 15) * 4;
    float4 v = *(const float4*)&Wl[(size_t)(k0 + r) * N + n0 + c4];
    Ls[c4 + 0][r] = (__bf16)v.x; Ls[c4 + 1][r] = (__bf16)v.y;
    Ls[c4 + 2][r] = (__bf16)v.z; Ls[c4 + 3][r] = (__bf16)v.w;
  }
  __syncthreads();
  #pragma unroll
  for (int p = 0; p < 4; ++p) {
    int e = tid + p * 256;
    int r2 = e >> 4, c8 = (e & 15) * 4;
    bf16x4 o{Ls[r2][c8], Ls[r2][c8 + 1], Ls[r2][c8 + 2], Ls[r2][c8 + 3]};
    *(bf16x4*)&Wtl[(size_t)(n0 + r2) * K + k0 + c8] = o;
  }
}

struct GemmP {
  const __bf16* A;
  const __bf16* W[3];   // [N][K] bf16
  const float* B[3];
  void* C[3];
  int N, K;
};

// C[M,N] = act(A[M,K] @ Wt[N,K]^T + bias). BN=128, BK=64.
// 2-phase dbuf staging (global_load_lds), pre-swizzled-source LDS swizzle,
// bijective XCD remap. BM in {32, 64, 128}.
template<int BM, int RELU, int OUTF32>
__global__ __launch_bounds__(256) void gemm_bf16(GemmP g) {
  constexpr int BK = 64;
  const __bf16* __restrict__ A = g.A;
  const __bf16* __restrict__ W = g.W[blockIdx.z];
  const float* __restrict__ bias = g.B[blockIdx.z];
  const int N = g.N, K = g.K;

  __shared__ __bf16 As[2][BM * BK];
  __shared__ __bf16 Bs[2][128 * BK];

  const int tid = threadIdx.x;
  const int lane = tid & 63, w = tid >> 6;

  const int gx = gridDim.x;
  const int nblk = gx * gridDim.y;
  const int id = blockIdx.x + blockIdx.y * gx;
  const int per = nblk >> 3;
  const int sid = (id & 7) * per + (id >> 3);
  const int row0 = (sid % gx) * BM;
  const int col0 = (sid / gx) * 128;

  const int wm = w >> 1, wn = w & 1;
  const int lr = lane & 15, rsw = lr & 7;

  constexpr int MI = BM / 32;
  f32x4 acc[MI][4] = {};

  const int swg = ((lane & 7) ^ (lane >> 3)) * 8;
  const __bf16* Ag = A + (size_t)(row0 + w * (BM / 4) + (lane >> 3)) * K + swg;
  const __bf16* Wg = W + (size_t)(col0 + w * 32 + (lane >> 3)) * K + swg;

  const int NT = K / BK;

  auto stage = [&](int buf, int t) {
    const int k0 = t * BK;
    #pragma unroll
    for (int s = 0; s < BM / 32; ++s)
      gll16(Ag + (size_t)s * 8 * K + k0, &As[buf][(w * (BM / 4) + s * 8) * BK]);
    #pragma unroll
    for (int s = 0; s < 4; ++s)
      gll16(Wg + (size_t)s * 8 * K + k0, &Bs[buf][(w * 32 + s * 8) * BK]);
  };

  stage(0, 0);
  __syncthreads();

  int cur = 0;
  for (int t = 0; t < NT; ++t) {
    if (t + 1 < NT) stage(cur ^ 1, t + 1);
    #pragma unroll
    for (int kk = 0; kk < 2; ++kk) {
      const int gsw = ((kk * 4 + (lane >> 4)) ^ rsw) * 8;
      bf16x8 af[MI], bf[4];
      #pragma unroll
      for (int i = 0; i < MI; ++i)
        af[i] = *(const bf16x8*)&As[cur][(wm * (BM / 2) + i * 16 + lr) * BK + gsw];
      #pragma unroll
      for (int j = 0; j < 4; ++j)
        bf[j] = *(const bf16x8*)&Bs[cur][(wn * 64 + j * 16 + lr) * BK + gsw];
      #pragma unroll
      for (int i = 0; i < MI; ++i)
        #pragma unroll
        for (int j = 0; j < 4; ++j)
          acc[i][j] = __builtin_amdgcn_mfma_f32_16x16x32_bf16(af[i], bf[j], acc[i][j], 0, 0, 0);
    }
    __syncthreads();
    cur ^= 1;
  }

  #pragma unroll
  for (int i = 0; i < MI; ++i) {
    #pragma unroll
    for (int j = 0; j < 4; ++j) {
      int col = col0 + wn * 64 + j * 16 + lr;
      float bb = bias[col];
      #pragma unroll
      for (int r = 0; r < 4; ++r) {
        int row = row0 + wm * (BM / 2) + i * 16 + (lane >> 4) * 4 + r;
        float v = acc[i][j][r] + bb;
        if (RELU) v = fmaxf(v, 0.0f);
        if (OUTF32) ((float*)g.C[blockIdx.z])[(size_t)row * N + col] = v;
        else ((__bf16*)g.C[blockIdx.z])[(size_t)row * N + col] = (__bf16)v;
      }
    }
  }
}

// 256x256-tile GEMM (2-phase, best measured for vocab). 512 thr = 8 waves,
// wave tile 128x64, BK=64, dbuf 128KB dynamic LDS.
__global__ __launch_bounds__(512, 1) void gemm_256(
    const __bf16* __restrict__ A, const __bf16* __restrict__ W,
    const float* __restrict__ bias, float* __restrict__ C, int N, int K) {
  extern __shared__ __bf16 sm[];
  __bf16* As = sm;                 // [2][256*64]
  __bf16* Bs = sm + 2 * 256 * 64;  // [2][256*64]

  const int tid = threadIdx.x;
  const int lane = tid & 63, w = tid >> 6;

  const int gx = gridDim.x;
  const int nblk = gx * gridDim.y;
  const int id = blockIdx.x + blockIdx.y * gx;
  const int per = nblk >> 3;
  const int sid = (id & 7) * per + (id >> 3);
  const int row0 = (sid % gx) * 256;
  const int col0 = (sid / gx) * 256;

  const int wr = w >> 2, wc = w & 3;
  const int lr = lane & 15;

  f32x4 acc[8][4] = {};

  const int swg = ((lane & 7) ^ (lane >> 3)) * 8;
  const __bf16* Ag = A + (size_t)(row0 + w * 32 + (lane >> 3)) * K + swg;
  const __bf16* Wg = W + (size_t)(col0 + w * 32 + (lane >> 3)) * K + swg;

  const int NT = K / 64;

  auto stage = [&](int buf, int t) {
    const int k0 = t * 64;
    #pragma unroll
    for (int s = 0; s < 4; ++s) {
      gll16(Ag + (size_t)(s * 8) * K + k0, &As[buf * 16384 + (w * 32 + s * 8) * 64]);
      gll16(Wg + (size_t)(s * 8) * K + k0, &Bs[buf * 16384 + (w * 32 + s * 8) * 64]);
    }
  };

  stage(0, 0);
  __syncthreads();

  int cur = 0;
  for (int t = 0; t < NT; ++t) {
    if (t + 1 < NT) stage(cur ^ 1, t + 1);
    #pragma unroll
    for (int kk = 0; kk < 2; ++kk) {
      bf16x8 af[8], bf[4];
      #pragma unroll
      for (int i = 0; i < 8; ++i) {
        int row = wr * 128 + i * 16 + lr;
        af[i] = *(const bf16x8*)&As[cur * 16384 + row * 64 +
                                    (((kk * 4 + (lane >> 4)) ^ (row & 7)) * 8)];
      }
      #pragma unroll
      for (int j = 0; j < 4; ++j) {
        int row = wc * 64 + j * 16 + lr;
        bf[j] = *(const bf16x8*)&Bs[cur * 16384 + row * 64 +
                                    (((kk * 4 + (lane >> 4)) ^ (row & 7)) * 8)];
      }
      #pragma unroll
      for (int i = 0; i < 8; ++i)
        #pragma unroll
        for (int j = 0; j < 4; ++j)
          acc[i][j] = __builtin_amdgcn_mfma_f32_16x16x32_bf16(af[i], bf[j], acc[i][j], 0, 0, 0);
    }
    __syncthreads();
    cur ^= 1;
  }

  #pragma unroll
  for (int i = 0; i < 8; ++i) {
    #pragma unroll
    for (int j = 0; j < 4; ++j) {
      int col = col0 + wc * 64 + j * 16 + lr;
      float bb = bias[col];
      #pragma unroll
      for (int r = 0; r < 4; ++r) {
        int row = row0 + wr * 128 + i * 16 + (lane >> 4) * 4 + r;
        C[(size_t)row * N + col] = acc[i][j][r] + bb;
      }
    }
  }
}

// MFMA flash attention, bf16 in/out. Causal-balanced: grid (8, B*H);
// block bx processes q-tiles bx and 15-bx -> every block = 17 chunk-iters.
__global__ __launch_bounds__(256) void attn_kernel(
    const __bf16* __restrict__ Q, const __bf16* __restrict__ K,
    const __bf16* __restrict__ V, __bf16* __restrict__ O) {
  __shared__ __bf16 Ks[64 * 64];      // [kv][d], swizzled
  __shared__ __bf16 Vts[64 * 64];     // [d][kv], swizzled
  __shared__ __bf16 Psm[4][16 * 64];  // per-wave P [q][kv], swizzled

  const int tid = threadIdx.x;
  const int lane = tid & 63, w = tid >> 6;
  const int bh = blockIdx.y;
  const int b = bh >> 4, h = bh & 15;
  const size_t base = ((size_t)b * SEQ) * D_MODEL + (size_t)h * DHEAD;

  const int lr = lane & 15;
  const int lk = (lane >> 4) * 8;
  const int NQT = SEQ / 64;  // 16

  #pragma unroll
  for (int p = 0; p < 2; ++p) {
    const int qt = p == 0 ? (int)blockIdx.x : (NQT - 1 - (int)blockIdx.x);
    const int q0 = qt * 64;

    bf16x8 qa[2];
    {
      const __bf16* qp = Q + base + (size_t)(q0 + w * 16 + lr) * D_MODEL;
      qa[0] = *(const bf16x8*)&qp[lk];
      qa[1] = *(const bf16x8*)&qp[32 + lk];
    }

    f32x4 o_acc[4] = {};
    float m[4], l[4];
    #pragma unroll
    for (int r = 0; r < 4; ++r) { m[r] = -1e30f; l[r] = 0.0f; }

    const int nck = qt + 1;

    for (int ck = 0; ck < nck; ++ck) {
      const int kv0 = ck * 64;
      __syncthreads();
      #pragma unroll
      for (int c = 0; c < 2; ++c) {
        int e = tid + c * 256;
        int r = e >> 3, d8 = (e & 7) * 8;
        const size_t grow = base + (size_t)(kv0 + r) * D_MODEL + d8;
        bf16x8 kv = *(const bf16x8*)&K[grow];
        *(bf16x8*)&Ks[(r * 64 + d8) ^ ((r & 7) << 3)] = kv;
        bf16x8 vv = *(const bf16x8*)&V[grow];
        #pragma unroll
        for (int j = 0; j < 8; ++j)
          Vts[((d8 + j) * 64 + r) ^ (((d8 + j) & 7) << 3)] = vv[j];
      }
      __syncthreads();

      f32x4 s_acc[4] = {};
      #pragma unroll
      for (int t = 0; t < 4; ++t) {
        int row = t * 16 + lr;
        #pragma unroll
        for (int hh = 0; hh < 2; ++hh) {
          bf16x8 kb = *(const bf16x8*)&Ks[(row * 64 + hh * 32 + lk) ^ ((row & 7) << 3)];
          s_acc[t] = __builtin_amdgcn_mfma_f32_16x16x32_bf16(qa[hh], kb, s_acc[t], 0, 0, 0);
        }
      }

      const bool diag = (ck == nck - 1);
      #pragma unroll
      for (int t = 0; t < 4; ++t) {
        int kvg = kv0 + t * 16 + lr;
        #pragma unroll
        for (int r = 0; r < 4; ++r) {
          float sv = s_acc[t][r] * 0.125f;
          if (diag) {
            int qg = q0 + w * 16 + (lane >> 4) * 4 + r;
            if (kvg > qg) sv = -1e30f;
          }
          s_acc[t][r] = sv;
        }
      }

      #pragma unroll
      for (int r = 0; r < 4; ++r) {
        float cm = fmaxf(fmaxf(s_acc[0][r], s_acc[1][r]), fmaxf(s_acc[2][r], s_acc[3][r]));
        #pragma unroll
        for (int off = 1; off < 16; off <<= 1) cm = fmaxf(cm, __shfl_xor(cm, off, 64));
        float newm = fmaxf(m[r], cm);
        float sc = __expf(m[r] - newm);
        m[r] = newm;
        float psum = 0.0f;
        #pragma unroll
        for (int t = 0; t < 4; ++t) {
          float pv = __expf(s_acc[t][r] - newm);
          s_acc[t][r] = pv;
          psum += pv;
        }
        #pragma unroll
        for (int off = 1; off < 16; off <<= 1) psum += __shfl_xor(psum, off, 64);
        l[r] = l[r] * sc + psum;
        #pragma unroll
        for (int t = 0; t < 4; ++t) o_acc[t][r] *= sc;
      }

      #pragma unroll
      for (int t = 0; t < 4; ++t) {
        #pragma unroll
        for (int r = 0; r < 4; ++r) {
          int ql = (lane >> 4) * 4 + r;
          Psm[w][(ql * 64 + t * 16 + lr) ^ ((ql & 7) << 3)] = (__bf16)(s_acc[t][r]);
        }
      }

      bf16x8 pa[2];
      #pragma unroll
      for (int hh = 0; hh < 2; ++hh)
        pa[hh] = *(const bf16x8*)&Psm[w][(lr * 64 + hh * 32 + lk) ^ ((lr & 7) << 3)];
      #pragma unroll
      for (int t = 0; t < 4; ++t) {
        int row = t * 16 + lr;
        #pragma unroll
        for (int hh = 0; hh < 2; ++hh) {
          bf16x8 vb = *(const bf16x8*)&Vts[(row * 64 + hh * 32 + lk) ^ ((row & 7) << 3)];
          o_acc[t] = __builtin_amdgcn_mfma_f32_16x16x32_bf16(pa[hh], vb, o_acc[t], 0, 0, 0);
        }
      }
    }

    #pragma unroll
    for (int r = 0; r < 4; ++r) {
      float inv = 1.0f / l[r];
      int qg = q0 + w * 16 + (lane >> 4) * 4 + r;
      #pragma unroll
      for (int t = 0; t < 4; ++t)
        O[base + (size_t)qg * D_MODEL + t * 16 + lr] = (__bf16)(o_acc[t][r] * inv);
    }
  }
}

// Out = LN(X (+ R)) * g + b. Wave-per-row: 4 rows/block, 64 lanes/row,
// 16 elems/lane, pure shfl reduction (no LDS, no barrier).
template<int HASRES>
__global__ __launch_bounds__(256) void addln_kernel(
    const __bf16* __restrict__ X, const __bf16* __restrict__ Rr,
    const float* __restrict__ g, const float* __restrict__ bb,
    __bf16* __restrict__ Out) {
  const int row = blockIdx.x * 4 + (threadIdx.x >> 6);
  const int lane = threadIdx.x & 63;
  const int d0 = lane * 16;
  const size_t rb = (size_t)row * D_MODEL + d0;

  bf16x8 x0 = *(const bf16x8*)&X[rb];
  bf16x8 x1 = *(const bf16x8*)&X[rb + 8];
  float v[16];
  float s = 0.0f, ss = 0.0f;
  if (HASRES) {
    bf16x8 r0 = *(const bf16x8*)&Rr[rb];
    bf16x8 r1 = *(const bf16x8*)&Rr[rb + 8];
    #pragma unroll
    for (int i = 0; i < 8; ++i) {
      v[i] = (float)x0[i] + (float)r0[i];
      v[8 + i] = (float)x1[i] + (float)r1[i];
    }
  } else {
    #pragma unroll
    for (int i = 0; i < 8; ++i) { v[i] = (float)x0[i]; v[8 + i] = (float)x1[i]; }
  }
  #pragma unroll
  for (int i = 0; i < 16; ++i) { s += v[i]; ss += v[i] * v[i]; }
  #pragma unroll
  for (int off = 32; off; off >>= 1) { s += __shfl_xor(s, off, 64); ss += __shfl_xor(ss, off, 64); }
  float mean = s * (1.0f / D_MODEL);
  float var = ss * (1.0f / D_MODEL) - mean * mean;
  float rs = rsqrtf(var + 1e-5f);

  bf16x8 o0, o1;
  #pragma unroll
  for (int c = 0; c < 4; ++c) {
    float4 gv = *(const float4*)&g[d0 + c * 4];
    float4 bv = *(const float4*)&bb[d0 + c * 4];
    float go[4] = {gv.x, gv.y, gv.z, gv.w};
    float bo[4] = {bv.x, bv.y, bv.z, bv.w};
    #pragma unroll
    for (int i = 0; i < 4; ++i) {
      int e = c * 4 + i;
      __bf16 r = (__bf16)((v[e] - mean) * rs * go[i] + bo[i]);
      if (e < 8) o0[e] = r; else o1[e - 8] = r;
    }
  }
  *(bf16x8*)&Out[rb] = o0;
  *(bf16x8*)&Out[rb + 8] = o1;
}

// H[row,d] = embed[x[row],d]*sqrt(D) + PE(row%S, d), bf16 out.
__global__ __launch_bounds__(256) void embed_kernel(
    const int* __restrict__ x, const float* __restrict__ embed,
    __bf16* __restrict__ H) {
  const int row = blockIdx.x;
  const int spos = row & (SEQ - 1);
  const int tok = x[row];
  const int tid = threadIdx.x;
  const int d0 = tid * 4;
  float4 e4 = *(const float4*)&embed[(size_t)tok * D_MODEL + d0];
  float ev[4] = {e4.x, e4.y, e4.z, e4.w};
  bf16x4 ov;
  #pragma unroll
  for (int p = 0; p < 2; ++p) {
    int d = d0 + 2 * p;
    float div = expf((float)d * (-9.2103403719761836f / (float)D_MODEL));
    float ang = (float)spos * div;
    float sv, cv;
    __sincosf(ang, &sv, &cv);
    ov[2 * p] = (__bf16)(ev[2 * p] * 32.0f + sv);
    ov[2 * p + 1] = (__bf16)(ev[2 * p + 1] * 32.0f + cv);
  }
  *(bf16x4*)&H[(size_t)row * D_MODEL + d0] = ov;
}

extern "C" void kernel_launch(void* const* d_in, const int* in_sizes, int n_in,
                              void* d_out, int out_size, void* d_ws, size_t ws_size,
                              hipStream_t stream) {
  const int* x = (const int*)d_in[0];
  const float* embed = (const float*)d_in[2];
  const float* wq = (const float*)d_in[3];
  const float* bq = (const float*)d_in[4];
  const float* wk = (const float*)d_in[5];
  const float* bk = (const float*)d_in[6];
  const float* wv = (const float*)d_in[7];
  const float* bv = (const float*)d_in[8];
  const float* wo = (const float*)d_in[9];
  const float* bo = (const float*)d_in[10];
  const float* w1 = (const float*)d_in[11];
  const float* b1 = (const float*)d_in[12];
  const float* w2 = (const float*)d_in[13];
  const float* b2 = (const float*)d_in[14];
  const float* ln1g = (const float*)d_in[15];
  const float* ln1b = (const float*)d_in[16];
  const float* ln2g = (const float*)d_in[17];
  const float* ln2b = (const float*)d_in[18];
  const float* lnfg = (const float*)d_in[19];
  const float* lnfb = (const float*)d_in[20];
  const float* pw = (const float*)d_in[21];
  const float* pb = (const float*)d_in[22];
  float* out = (float*)d_out;

  // ---- workspace layout (bf16) ----
  char* wsp = (char*)d_ws;
  size_t off = 0;
  auto alloc = [&](size_t bytes) {
    void* p = wsp + off; off = (off + bytes + 255) & ~(size_t)255; return p;
  };
  const size_t RD2 = (size_t)NROWS * D_MODEL * 2;
  __bf16* Xb   = (__bf16*)alloc(RD2);
  __bf16* Qb   = (__bf16*)alloc(RD2);
  __bf16* Kb   = (__bf16*)alloc(RD2);
  __bf16* Vb   = (__bf16*)alloc(RD2);
  __bf16* CTXb = (__bf16*)alloc(RD2);
  __bf16* Tb   = (__bf16*)alloc(RD2);
  __bf16* H1b  = (__bf16*)alloc(RD2);
  __bf16* FFb  = Qb;  // alias: FF (16MB) over Qb..CTXb, dead when FFN1 runs
  const size_t DD = (size_t)D_MODEL * D_MODEL;
  const size_t DF = (size_t)D_MODEL * FDIM;
  __bf16* wqt = (__bf16*)alloc(NLAYERS * DD * 2);
  __bf16* wkt = (__bf16*)alloc(NLAYERS * DD * 2);
  __bf16* wvt = (__bf16*)alloc(NLAYERS * DD * 2);
  __bf16* wot = (__bf16*)alloc(NLAYERS * DD * 2);
  __bf16* w1t = (__bf16*)alloc(NLAYERS * DF * 2);
  __bf16* w2t = (__bf16*)alloc(NLAYERS * DF * 2);
  __bf16* pwt = (__bf16*)alloc((size_t)D_MODEL * VOCAB * 2);

  // ---- weight transpose+convert (runs each replay) ----
  transpose_w<<<dim3(16, 16, NLAYERS), 256, 0, stream>>>(wq, wqt, D_MODEL, D_MODEL);
  transpose_w<<<dim3(16, 16, NLAYERS), 256, 0, stream>>>(wk, wkt, D_MODEL, D_MODEL);
  transpose_w<<<dim3(16, 16, NLAYERS), 256, 0, stream>>>(wv, wvt, D_MODEL, D_MODEL);
  transpose_w<<<dim3(16, 16, NLAYERS), 256, 0, stream>>>(wo, wot, D_MODEL, D_MODEL);
  transpose_w<<<dim3(64, 16, NLAYERS), 256, 0, stream>>>(w1, w1t, D_MODEL, FDIM);
  transpose_w<<<dim3(16, 64, NLAYERS), 256, 0, stream>>>(w2, w2t, FDIM, D_MODEL);
  transpose_w<<<dim3(500, 16, 1), 256, 0, stream>>>(pw, pwt, D_MODEL, VOCAB);

  embed_kernel<<<NROWS, 256, 0, stream>>>(x, embed, Xb);

  for (int l = 0; l < NLAYERS; ++l) {
    GemmP g{};
    g.A = Xb; g.N = D_MODEL; g.K = D_MODEL;
    g.W[0] = wqt + l * DD; g.W[1] = wkt + l * DD; g.W[2] = wvt + l * DD;
    g.B[0] = bq + l * D_MODEL; g.B[1] = bk + l * D_MODEL; g.B[2] = bv + l * D_MODEL;
    g.C[0] = Qb; g.C[1] = Kb; g.C[2] = Vb;
    gemm_bf16<64, 0, 0><<<dim3(NROWS / 64, D_MODEL / 128, 3), 256, 0, stream>>>(g);

    attn_kernel<<<dim3(SEQ / 128, BATCH * NHEADS), 256, 0, stream>>>(Qb, Kb, Vb, CTXb);

    GemmP go{};
    go.A = CTXb; go.N = D_MODEL; go.K = D_MODEL;
    go.W[0] = wot + l * DD; go.B[0] = bo + l * D_MODEL; go.C[0] = Tb;
    gemm_bf16<32, 0, 0><<<dim3(NROWS / 32, D_MODEL / 128, 1), 256, 0, stream>>>(go);

    addln_kernel<1><<<NROWS / 4, 256, 0, stream>>>(Xb, Tb, ln1g + l * D_MODEL, ln1b + l * D_MODEL, H1b);

    GemmP g1{};
    g1.A = H1b; g1.N = FDIM; g1.K = D_MODEL;
    g1.W[0] = w1t + l * DF; g1.B[0] = b1 + l * FDIM; g1.C[0] = FFb;
    gemm_bf16<128, 1, 0><<<dim3(NROWS / 128, FDIM / 128, 1), 256, 0, stream>>>(g1);

    GemmP g2{};
    g2.A = FFb; g2.N = D_MODEL; g2.K = FDIM;
    g2.W[0] = w2t + l * DF; g2.B[0] = b2 + l * D_MODEL; g2.C[0] = Tb;
    gemm_bf16<32, 0, 0><<<dim3(NROWS / 32, D_MODEL / 128, 1), 256, 0, stream>>>(g2);

    addln_kernel<1><<<NROWS / 4, 256, 0, stream>>>(H1b, Tb, ln2g + l * D_MODEL, ln2b + l * D_MODEL, Xb);
  }

  addln_kernel<0><<<NROWS / 4, 256, 0, stream>>>(Xb, nullptr, lnfg, lnfb, H1b);

  // vocab projection: 256x256-tile 2-phase kernel, 128KB dynamic LDS
  hipFuncSetAttribute((const void*)gemm_256,
                      hipFuncAttributeMaxDynamicSharedMemorySize, 131072);
  gemm_256<<<dim3(NROWS / 256, VOCAB / 256), 512, 131072, stream>>>(
      H1b, pwt, pb, out, VOCAB, D_MODEL);
}